// Round 7
// baseline (455.815 us; speedup 1.0000x reference)
//
#include <hip/hip_runtime.h>
#include <hip/hip_fp16.h>
#include <math.h>

#define CAP 48       // max CSR in-degree (layer-2 only); P(deg>=48) ~ 8e-11/node
#define PARTBITS 7   // 128 dsts per bin -> 782 bins
#define BINW 128
#define NB 128       // routing blocks == segments/bin (4 thr/seg at 512 thr)
#define SEGCAP 40    // per-(bin,block) queue segment; mean 16.0, ~6 sigma

typedef float f32x4 __attribute__((ext_vector_type(4)));
typedef __bf16 bf16x8 __attribute__((ext_vector_type(8)));
typedef unsigned short ushort8 __attribute__((ext_vector_type(8)));
typedef unsigned short ushort4v __attribute__((ext_vector_type(4)));
typedef int i32x4 __attribute__((ext_vector_type(4)));
typedef unsigned u32x4 __attribute__((ext_vector_type(4)));

__device__ __forceinline__ float leaky(float x){ return x > 0.f ? x : 0.2f * x; }
__device__ __forceinline__ float eluf(float x){ return x > 0.f ? x : __expf(x) - 1.f; }
__device__ __forceinline__ unsigned short f2bf(float f){  // RNE float->bf16
  unsigned u = __float_as_uint(f);
  u += 0x7FFF + ((u >> 16) & 1);
  return (unsigned short)(u >> 16);
}
__device__ __forceinline__ float bf2f(unsigned short u){
  return __uint_as_float(((unsigned)u) << 16);
}
__device__ __forceinline__ unsigned short f2h(float f){
  return __half_as_ushort(__float2half(f));
}
__device__ __forceinline__ float h2f(unsigned short u){
  return __half2float(__ushort_as_half(u));
}

// K12a (R22): fused k1 (node records + Bfrag prepack) and k2a (edge routing).
// Node record recD (stride 16 ushorts = 32B): [x0..x5 bf16][as0..as3 f16][pad2].
// recC: per-node a_dst (4 f16). Queue entries packed to 4B:
// (src << PARTBITS) | (dst & (BINW-1)); bin implied by queue position.
__global__ __launch_bounds__(256) void k12a(const float* __restrict__ x,
    const float* __restrict__ W1, const float* __restrict__ as1,
    const float* __restrict__ ad1, const float* __restrict__ W2,
    unsigned short* __restrict__ Bfrag, unsigned short* __restrict__ recD,
    ushort4v* __restrict__ recC,
    int* __restrict__ gtail, int N, int nbk1,
    const int* __restrict__ ei, int E, int NR,
    unsigned* __restrict__ queue, int* __restrict__ qcnt){
  __shared__ float vw[48];
  __shared__ int lcnt[800];
  int t = threadIdx.x;
  if ((int)blockIdx.x < nbk1){
    int gid = blockIdx.x * 256 + t;
    if (gid == 0) *gtail = 0;   // CSR allocator, consumed by k2b34 CSR phase
    if (gid < 16384){
      int j  = gid & 7;
      int L  = (gid >> 3) & 63;
      int ct = (gid >> 9) & 3;
      int ks = gid >> 11;
      int k = ks*32 + ((L >> 4) & 3)*8 + j;
      int c = ct*16 + (L & 15);
      Bfrag[gid] = f2bf(W2[k*64 + c]);
    }
    if (t < 48){
      int side = t / 24, r = t % 24, f = r / 4, h = r % 4;
      const float* att = side ? ad1 : as1;
      float s = 0.f;
      for (int c = 0; c < 64; ++c) s += W1[f*256 + h*64 + c] * att[h*64 + c];
      vw[side*24 + f*4 + h] = s;
    }
    __syncthreads();
    int n = gid;
    if (n >= N) return;
    float xf[6];
    for (int f = 0; f < 6; ++f) xf[f] = x[n*6 + f];
    float as[4], ad[4];
    for (int h = 0; h < 4; ++h){
      float s = 0.f, d = 0.f;
      for (int f = 0; f < 6; ++f){ s += xf[f] * vw[f*4 + h]; d += xf[f] * vw[24 + f*4 + h]; }
      as[h] = s; ad[h] = d;
    }
    ushort8 v8;
    v8[0]=f2bf(xf[0]); v8[1]=f2bf(xf[1]); v8[2]=f2bf(xf[2]); v8[3]=f2bf(xf[3]);
    v8[4]=f2bf(xf[4]); v8[5]=f2bf(xf[5]); v8[6]=f2h(as[0]); v8[7]=f2h(as[1]);
    ushort4v v4 = {f2h(as[2]), f2h(as[3]), 0, 0};
    *(ushort8*)(recD + (size_t)n*16) = v8;
    *(ushort4v*)(recD + (size_t)n*16 + 8) = v4;
    recC[n] = (ushort4v){f2h(ad[0]), f2h(ad[1]), f2h(ad[2]), f2h(ad[3])};
  } else {
    int blk = blockIdx.x - nbk1;
    for (int i = t; i < NR; i += 256) lcnt[i] = 0;
    __syncthreads();
    int E4 = E >> 2;
    const i32x4* s4 = (const i32x4*)ei;
    const i32x4* d4 = (const i32x4*)(ei + E);
    for (int i = blk*256 + t; i < E4; i += NB*256){
      i32x4 s = __builtin_nontemporal_load(s4 + i);
      i32x4 d = __builtin_nontemporal_load(d4 + i);
      #pragma unroll
      for (int j = 0; j < 4; ++j){
        int p = d[j] >> PARTBITS;
        int r = atomicAdd(&lcnt[p], 1);
        if (r < SEGCAP){
          unsigned v = ((unsigned)s[j] << PARTBITS) | ((unsigned)d[j] & (BINW-1u));
          queue[((size_t)p*NB + blk)*SEGCAP + r] = v;
        }
      }
    }
    if (blk == 0 && t < (E & 3)){
      int e = E4*4 + t;
      int dd = ei[E + e], ss = ei[e];
      int p = dd >> PARTBITS;
      int r = atomicAdd(&lcnt[p], 1);
      if (r < SEGCAP){
        unsigned v = ((unsigned)ss << PARTBITS) | ((unsigned)dd & (BINW-1u));
        queue[((size_t)p*NB + blk)*SEGCAP + r] = v;
      }
    }
    __syncthreads();
    for (int i = t; i < NR; i += 256) qcnt[(size_t)i*NB + blk] = lcnt[i];
  }
}

// K2b34 (R22): EDGE-PARALLEL layer-1 aggregation via LDS atomics + layer-1
// matmul + layer-2 projection. One 512-thread block per 128-node bin.
//   Init:    self-loop terms seed acc[128][4][7] (plain writes); a_dst->LDS.
//            Non-drone bins stage W1/b1/Bfrag NOW (hidden under edge loop);
//            drone bins (79/782) build lbuck+CSR for k5 instead.
//   Edge loop: 4 thr/segment iterate the bin's queue directly — per edge ONE
//            thread loads recD (20B), computes 4 heads, 28 ds_add_f32.
//            No bucket build, no degree imbalance, no redundant loads.
//   Normalize: acc->regs, barrier, write afs (aliases acc low 6KB).
//   Phase D: unchanged MFMA body (af once via 3x ds_read_b128, B from LDS).
__global__ __launch_bounds__(512) void k2b34(const unsigned* __restrict__ queue,
    const int* __restrict__ qcnt,
    const unsigned short* __restrict__ recD, const ushort4v* __restrict__ recC,
    int* __restrict__ cnt, int* __restrict__ row_start,
    int* __restrict__ bucket, int* __restrict__ gtail,
    const float* __restrict__ W1, const float* __restrict__ b1,
    const unsigned short* __restrict__ Bfrag,
    const float* __restrict__ as2v, const float* __restrict__ ad2v,
    unsigned short* __restrict__ h2h, float* __restrict__ a2s,
    float* __restrict__ a2d, int nd_bins, int N){
  __shared__ float accf[BINW*28];              // 14336B; afs aliases low 6144B
  __shared__ ushort4v adl[BINW];               // 1KB a_dst
  __shared__ int lc[BINW];
  __shared__ int scan[BINW];
  __shared__ int gbase_s;
  __shared__ union {
    int lbuck[BINW*CAP];                       // 24KB (drone-bin CSR only)
    struct { float w1s[6*256]; float b1s[256]; ushort8 bfs[2048]; } d;  // 39KB
  } u;
  unsigned short* afs = (unsigned short*)accf;
  int t = threadIdx.x, bin = blockIdx.x;

  // ---- init: a_dst stage + self-loop accumulator seed ----
  if (t < BINW){ adl[t] = recC[(size_t)bin*BINW + t]; lc[t] = 0; }
  {
    int dl = t >> 2, h = t & 3;
    size_t n = (size_t)bin*BINW + dl;
    ushort8 lo = *(const ushort8*)(recD + n*16);
    unsigned a23 = *(const unsigned*)(recD + n*16 + 8);
    float xf[6];
    #pragma unroll
    for (int f = 0; f < 6; ++f) xf[f] = bf2f(lo[f]);
    unsigned short ash = (h==0) ? lo[6] : (h==1) ? lo[7]
                       : (h==2) ? (unsigned short)(a23 & 0xffffu)
                                : (unsigned short)(a23 >> 16);
    ushort4v cc = recC[n];
    float e0 = __expf(leaky(h2f(ash) + h2f(cc[h])));
    float* ab = &accf[dl*28 + h*7];
    #pragma unroll
    for (int f = 0; f < 6; ++f) ab[f] = e0 * xf[f];
    ab[6] = e0;
  }
  // ---- drone bins: lbuck + CSR for k5; others: stage weights early ----
  if (bin < nd_bins){
    __syncthreads();   // lc zero visible
    {
      int seg = t >> 2;
      int lq = min(qcnt[(size_t)bin*NB + seg], SEGCAP);
      const unsigned* qs = queue + ((size_t)bin*NB + seg)*SEGCAP;
      for (int b = (t & 3)*4; b < lq; b += 16){
        u32x4 v = *(const u32x4*)(qs + b);
        #pragma unroll
        for (int k = 0; k < 4; ++k){
          if (b + k < lq){
            unsigned pr = v[k];
            int ld = (int)(pr & (BINW-1u));
            int pos = atomicAdd(&lc[ld], 1);
            if (pos < CAP) u.lbuck[ld*CAP + pos] = (int)(pr >> PARTBITS);
          }
        }
      }
    }
    __syncthreads();
    if (t < BINW) scan[t] = min(lc[t], CAP);
    __syncthreads();
    for (int off = 1; off < BINW; off <<= 1){
      int v = 0;
      if (t < BINW && t >= off) v = scan[t - off];
      __syncthreads();
      if (t < BINW) scan[t] += v;
      __syncthreads();
    }
    if (t == 0) gbase_s = atomicAdd(gtail, scan[BINW-1]);
    __syncthreads();
    int gbase = gbase_s;
    int Vn = scan[BINW-1];
    for (int vi = t; vi < Vn; vi += 512){
      int lo = 0, hi = BINW-1;
      while (lo < hi){ int mid = (lo+hi) >> 1; if (scan[mid] <= vi) lo = mid+1; else hi = mid; }
      int base0 = lo ? scan[lo-1] : 0;
      bucket[gbase + vi] = u.lbuck[lo*CAP + (vi - base0)];
    }
    if (t < BINW){
      cnt[bin*BINW + t] = min(lc[t], CAP);
      row_start[bin*BINW + t] = gbase + (t ? scan[t-1] : 0);
    }
  } else {
    if (t < 384) ((float4*)u.d.w1s)[t] = ((const float4*)W1)[t];
    if (t < 64) ((float4*)u.d.b1s)[t] = ((const float4*)b1)[t];
    const ushort8* bfg = (const ushort8*)Bfrag;
    #pragma unroll
    for (int i = 0; i < 4; ++i) u.d.bfs[t + 512*i] = bfg[t + 512*i];
  }
  __syncthreads();
  // ---- edge loop: 4 thr/segment, all 4 heads per edge, LDS atomics ----
  {
    int seg = t >> 2;
    int lq = min(qcnt[(size_t)bin*NB + seg], SEGCAP);
    const unsigned* qs = queue + ((size_t)bin*NB + seg)*SEGCAP;
    for (int b = (t & 3)*4; b < lq; b += 16){
      u32x4 v = *(const u32x4*)(qs + b);
      #pragma unroll
      for (int k = 0; k < 4; ++k){
        if (b + k < lq){
          unsigned pr = v[k];
          size_t s = (size_t)(pr >> PARTBITS);
          int dl = (int)(pr & (BINW-1u));
          ushort8 lo = *(const ushort8*)(recD + s*16);
          unsigned a23 = *(const unsigned*)(recD + s*16 + 8);
          float xf[6];
          #pragma unroll
          for (int f = 0; f < 6; ++f) xf[f] = bf2f(lo[f]);
          float as4[4] = {h2f(lo[6]), h2f(lo[7]),
                          h2f((unsigned short)(a23 & 0xffffu)),
                          h2f((unsigned short)(a23 >> 16))};
          ushort4v ad4 = adl[dl];
          float* ab = &accf[dl*28];
          #pragma unroll
          for (int h = 0; h < 4; ++h){
            float e = __expf(leaky(as4[h] + h2f(ad4[h])));
            atomicAdd(&ab[h*7 + 6], e);
            #pragma unroll
            for (int f = 0; f < 6; ++f) atomicAdd(&ab[h*7 + f], e * xf[f]);
          }
        }
      }
    }
  }
  __syncthreads();
  // ---- normalize (read acc -> regs); drone bins stage weights now ----
  unsigned wo0, wo1, wo2;
  {
    int dl = t >> 2, h = t & 3;
    const float* ab = &accf[dl*28 + h*7];
    float v0=ab[0], v1=ab[1], v2=ab[2], v3=ab[3], v4=ab[4], v5=ab[5], dn=ab[6];
    float dinv = 1.f / dn;
    wo0 = (unsigned)f2h(v0*dinv) | ((unsigned)f2h(v1*dinv) << 16);
    wo1 = (unsigned)f2h(v2*dinv) | ((unsigned)f2h(v3*dinv) << 16);
    wo2 = (unsigned)f2h(v4*dinv) | ((unsigned)f2h(v5*dinv) << 16);
  }
  if (bin < nd_bins){
    if (t < 384) ((float4*)u.d.w1s)[t] = ((const float4*)W1)[t];
    if (t < 64) ((float4*)u.d.b1s)[t] = ((const float4*)b1)[t];
    const ushort8* bfg = (const ushort8*)Bfrag;
    #pragma unroll
    for (int i = 0; i < 4; ++i) u.d.bfs[t + 512*i] = bfg[t + 512*i];
  }
  __syncthreads();
  {
    int dl = t >> 2, h = t & 3;
    unsigned* ao = (unsigned*)(afs + dl*24 + h*6);  // byte off dl*48+h*12, 4B-aligned
    ao[0] = wo0; ao[1] = wo1; ao[2] = wo2;
  }
  __syncthreads();
  // ---- phase D: MFMA body; 2 groups of 256 threads, 64 nodes each ----
  {
    int grp = t >> 8;           // 0..1
    int t2  = t & 255;
    int L = t2 & 63;
    int w = t2 >> 6;
    int m = L & 15;
    int quad = L >> 4;
    int base = bin*BINW + grp*64;
    int nl = grp*64 + w*16 + m;         // 0..127 row in afs
    ushort8 u0 = *(const ushort8*)(afs + nl*24);
    ushort8 u1 = *(const ushort8*)(afs + nl*24 + 8);
    ushort8 u2 = *(const ushort8*)(afs + nl*24 + 16);
    f32x4 acc[4];
    #pragma unroll
    for (int ct = 0; ct < 4; ++ct) acc[ct] = (f32x4){0.f, 0.f, 0.f, 0.f};
    #pragma unroll
    for (int ks = 0; ks < 8; ++ks){
      int kb = ks*32 + quad*8;
      int kc = kb >> 6;
      float4 bb0 = *(const float4*)(u.d.b1s + kb);
      float4 bb1 = *(const float4*)(u.d.b1s + kb + 4);
      float s0=bb0.x, s1=bb0.y, s2=bb0.z, s3=bb0.w;
      float s4=bb1.x, s5=bb1.y, s6=bb1.z, s7=bb1.w;
      #pragma unroll
      for (int f = 0; f < 6; ++f){
        int e = kc*6 + f;   // compile-time after unroll
        unsigned short ah = (e < 8) ? u0[e] : ((e < 16) ? u1[e-8] : u2[e-16]);
        float a = h2f(ah);
        float4 w0 = *(const float4*)(u.d.w1s + f*256 + kb);
        float4 w1 = *(const float4*)(u.d.w1s + f*256 + kb + 4);
        s0 += a*w0.x; s1 += a*w0.y; s2 += a*w0.z; s3 += a*w0.w;
        s4 += a*w1.x; s5 += a*w1.y; s6 += a*w1.z; s7 += a*w1.w;
      }
      ushort8 ap;
      ap[0]=f2bf(eluf(s0)); ap[1]=f2bf(eluf(s1)); ap[2]=f2bf(eluf(s2)); ap[3]=f2bf(eluf(s3));
      ap[4]=f2bf(eluf(s4)); ap[5]=f2bf(eluf(s5)); ap[6]=f2bf(eluf(s6)); ap[7]=f2bf(eluf(s7));
      bf16x8 av = __builtin_bit_cast(bf16x8, ap);
      #pragma unroll
      for (int ct = 0; ct < 4; ++ct){
        bf16x8 bv = __builtin_bit_cast(bf16x8, u.d.bfs[(ks*4 + ct)*64 + L]);
        acc[ct] = __builtin_amdgcn_mfma_f32_16x16x32_bf16(av, bv, acc[ct], 0, 0, 0);
      }
    }
    float asv[4], adv[4];
    #pragma unroll
    for (int ct = 0; ct < 4; ++ct){ asv[ct] = as2v[ct*16 + m]; adv[ct] = ad2v[ct*16 + m]; }
    float ps[4] = {0,0,0,0}, pd[4] = {0,0,0,0};
    #pragma unroll
    for (int ct = 0; ct < 4; ++ct)
      #pragma unroll
      for (int r = 0; r < 4; ++r){
        ps[r] += acc[ct][r] * asv[ct];
        pd[r] += acc[ct][r] * adv[ct];
      }
    #pragma unroll
    for (int r = 0; r < 4; ++r){
      int nr = base + w*16 + quad*4 + r;
      if (nr < N){
        #pragma unroll
        for (int ct = 0; ct < 4; ++ct)
          h2h[(size_t)nr*64 + ct*16 + m] = f2h(acc[ct][r]);
      }
    }
    #pragma unroll
    for (int mask = 1; mask <= 8; mask <<= 1){
      #pragma unroll
      for (int r = 0; r < 4; ++r){
        ps[r] += __shfl_xor(ps[r], mask, 64);
        pd[r] += __shfl_xor(pd[r], mask, 64);
      }
    }
    if (m == 0){
      #pragma unroll
      for (int r = 0; r < 4; ++r){
        int nr = base + w*16 + quad*4 + r;
        if (nr < N){ a2s[nr] = ps[r]; a2d[nr] = pd[r]; }
      }
    }
  }
}

// K5: layer-2 aggregation only for drone dsts (first ND) + elu + MLP head.
__global__ __launch_bounds__(256) void k5_out(
    const unsigned short* __restrict__ h2h, const float* __restrict__ a2s,
    const float* __restrict__ a2d, const int* __restrict__ cnt,
    const int* __restrict__ row_start, const int* __restrict__ bucket,
    const float* __restrict__ b2, const float* __restrict__ fc1w,
    const float* __restrict__ fc1b, const float* __restrict__ fc2w,
    const float* __restrict__ fc2b, float* __restrict__ out, int ND){
  __shared__ float hb[4][64];
  int lane = threadIdx.x & 63;
  int w = threadIdx.x >> 6;
  int n = blockIdx.x * 4 + w;
  if (n >= ND) return;
  float adv = a2d[n];
  float e0 = __expf(leaky(a2s[n] + adv));
  float den = e0;
  float acc = e0 * h2f(h2h[(size_t)n*64 + lane]);
  int deg = cnt[n];
  const int* bk = bucket + row_start[n];
  int i = 0;
  for (; i + 4 <= deg; i += 4){
    int sid[4];
    #pragma unroll
    for (int j = 0; j < 4; ++j) sid[j] = bk[i+j];
    float av[4]; unsigned short hv4[4];
    #pragma unroll
    for (int j = 0; j < 4; ++j){
      av[j] = a2s[sid[j]];
      hv4[j] = h2h[(size_t)sid[j]*64 + lane];
    }
    #pragma unroll
    for (int j = 0; j < 4; ++j){
      float e = __expf(leaky(av[j] + adv));
      den += e;
      acc += e * h2f(hv4[j]);
    }
  }
  for (; i < deg; ++i){
    int s = bk[i];
    float e = __expf(leaky(a2s[s] + adv));
    den += e;
    acc += e * h2f(h2h[(size_t)s*64 + lane]);
  }
  float hv = eluf(acc / den + b2[lane]);
  hb[w][lane] = hv;               // wave-local LDS (lockstep wave64)
  float t1 = fc1b[lane];
  for (int k = 0; k < 64; ++k) t1 += hb[w][k] * fc1w[k*64 + lane];
  t1 = fmaxf(t1, 0.f);
  float p0 = t1 * fc2w[lane*2 + 0];
  float p1 = t1 * fc2w[lane*2 + 1];
  for (int o = 32; o > 0; o >>= 1){
    p0 += __shfl_down(p0, o, 64);
    p1 += __shfl_down(p1, o, 64);
  }
  if (lane == 0){
    out[n*2 + 0] = tanhf(p0 + fc2b[0]) * 2.f;
    out[n*2 + 1] = tanhf(p1 + fc2b[1]) * 2.f;
  }
}

extern "C" void kernel_launch(void* const* d_in, const int* in_sizes, int n_in,
                              void* d_out, int out_size, void* d_ws, size_t ws_size,
                              hipStream_t stream){
  const float* x    = (const float*)d_in[0];
  const int*   ei   = (const int*)d_in[1];    // harness passes integers as int32
  const float* W1   = (const float*)d_in[3];
  const float* as1  = (const float*)d_in[4];
  const float* ad1  = (const float*)d_in[5];
  const float* b1   = (const float*)d_in[6];
  const float* W2   = (const float*)d_in[7];
  const float* as2  = (const float*)d_in[8];
  const float* ad2  = (const float*)d_in[9];
  const float* b2   = (const float*)d_in[10];
  const float* fc1w = (const float*)d_in[11];
  const float* fc1b = (const float*)d_in[12];
  const float* fc2w = (const float*)d_in[13];
  const float* fc2b = (const float*)d_in[14];
  float* out = (float*)d_out;

  int N  = in_sizes[0] / 6;
  int E  = in_sizes[1] / 2;
  int ND = out_size / 2;
  int NR = (N + BINW - 1) >> PARTBITS;   // number of dst bins (782)
  int nd_bins = (ND + BINW - 1) / BINW;  // bins containing drone dsts (k5)
  int nbk1 = (N + 255) / 256;
  int NC = NR * BINW;                    // padded node count

  char* p = (char*)d_ws;
  auto alloc = [&](size_t bytes){ void* r = (void*)p; p += (bytes + 255) & ~(size_t)255; return r; };
  int*            cnt    = (int*)           alloc((size_t)NC * 4);
  int*            rowst  = (int*)           alloc((size_t)NC * 4);
  int*            bucket = (int*)           alloc(((size_t)E + 1024) * 4);   // CSR (drone bins only)
  unsigned short* recD   = (unsigned short*)alloc((size_t)NC * 32);
  ushort4v*       recC   = (ushort4v*)      alloc((size_t)NC * 8);
  unsigned short* h2h    = (unsigned short*)alloc((size_t)N * 128);
  float*          a2s    = (float*)         alloc((size_t)N * 4);
  float*          a2d    = (float*)         alloc((size_t)N * 4);
  unsigned short* Bfrag  = (unsigned short*)alloc(16384 * 2);
  unsigned*       queue  = (unsigned*)      alloc((size_t)NR * NB * SEGCAP * 4);
  int*            qcnt   = (int*)           alloc((size_t)NR * NB * 4);
  int*            gtail  = (int*)           alloc(256);

  size_t needed = (size_t)(p - (char*)d_ws);
  if (needed > ws_size) return;   // clean fail instead of GPU fault

  k12a<<<nbk1 + NB, 256, 0, stream>>>(x, W1, as1, ad1, W2, Bfrag, recD, recC,
                                      gtail, N, nbk1, ei, E, NR, queue, qcnt);
  k2b34<<<NR, 512, 0, stream>>>(queue, qcnt, recD, recC,
                                cnt, rowst, bucket, gtail,
                                W1, b1, Bfrag, as2, ad2,
                                h2h, a2s, a2d, nd_bins, N);
  k5_out<<<(ND + 3)/4, 256, 0, stream>>>(h2h, a2s, a2d, cnt, rowst, bucket, b2,
                                         fc1w, fc1b, fc2w, fc2b, out, ND);
}

// Round 8
// 173.294 us; speedup vs baseline: 2.6303x; 2.6303x over previous
//
#include <hip/hip_runtime.h>
#include <hip/hip_fp16.h>
#include <math.h>

#define CAP 48       // max bucketed in-degree; Poisson(16), P(deg>=48) ~ 8e-11/node
#define PARTBITS 8   // 256 dsts per bin
#define BINW 256
#define NB 240       // routing blocks
#define SEGCAP 48    // per-(bin,block) queue segment; mean 17, 7.5 sigma

typedef float f32x4 __attribute__((ext_vector_type(4)));
typedef __bf16 bf16x8 __attribute__((ext_vector_type(8)));
typedef unsigned short ushort8 __attribute__((ext_vector_type(8)));
typedef unsigned short ushort4v __attribute__((ext_vector_type(4)));
typedef int i32x4 __attribute__((ext_vector_type(4)));
typedef int i32x2 __attribute__((ext_vector_type(2)));

__device__ __forceinline__ float leaky(float x){ return x > 0.f ? x : 0.2f * x; }
__device__ __forceinline__ float eluf(float x){ return x > 0.f ? x : __expf(x) - 1.f; }
__device__ __forceinline__ unsigned short f2bf(float f){  // RNE float->bf16
  unsigned u = __float_as_uint(f);
  u += 0x7FFF + ((u >> 16) & 1);
  return (unsigned short)(u >> 16);
}
__device__ __forceinline__ float bf2f(unsigned short u){
  return __uint_as_float(((unsigned)u) << 16);
}
__device__ __forceinline__ unsigned short f2h(float f){
  return __half_as_ushort(__float2half(f));
}
__device__ __forceinline__ float h2f(unsigned short u){
  return __half2float(__ushort_as_half(u));
}

// K12a: fused k1 (node records + Bfrag prepack) and k2a (edge routing).
// EXACT R0/R15 version (replay-proven).
__global__ __launch_bounds__(256) void k12a(const float* __restrict__ x,
    const float* __restrict__ W1, const float* __restrict__ as1,
    const float* __restrict__ ad1, const float* __restrict__ W2,
    unsigned short* __restrict__ Bfrag, ushort8* __restrict__ recA,
    ushort8* __restrict__ recB, ushort4v* __restrict__ recC,
    int* __restrict__ gtail, int N, int nbk1,
    const int* __restrict__ ei, int E, int NR,
    i32x2* __restrict__ queue, int* __restrict__ qcnt){
  __shared__ float vw[48];
  __shared__ int lcnt[512];
  int t = threadIdx.x;
  if ((int)blockIdx.x < nbk1){
    int gid = blockIdx.x * 256 + t;
    if (gid == 0) *gtail = 0;   // CSR allocator, consumed by k2b3
    if (gid < 16384){
      int j  = gid & 7;
      int L  = (gid >> 3) & 63;
      int ct = (gid >> 9) & 3;
      int ks = gid >> 11;
      int k = ks*32 + ((L >> 4) & 3)*8 + j;
      int c = ct*16 + (L & 15);
      Bfrag[gid] = f2bf(W2[k*64 + c]);
    }
    if (t < 48){
      int side = t / 24, r = t % 24, f = r / 4, h = r % 4;
      const float* att = side ? ad1 : as1;
      float s = 0.f;
      for (int c = 0; c < 64; ++c) s += W1[f*256 + h*64 + c] * att[h*64 + c];
      vw[side*24 + f*4 + h] = s;
    }
    __syncthreads();
    int n = gid;
    if (n >= N) return;
    float xf[6];
    for (int f = 0; f < 6; ++f) xf[f] = x[n*6 + f];
    float as[4], ad[4];
    for (int h = 0; h < 4; ++h){
      float s = 0.f, d = 0.f;
      for (int f = 0; f < 6; ++f){ s += xf[f] * vw[f*4 + h]; d += xf[f] * vw[24 + f*4 + h]; }
      as[h] = s; ad[h] = d;
    }
    ushort8 va, vb;
    va[0]=f2bf(xf[0]); va[1]=f2bf(xf[1]); va[2]=f2bf(xf[2]); va[3]=f2bf(xf[3]);
    va[4]=f2bf(xf[4]); va[5]=f2bf(xf[5]); va[6]=f2h(as[0]); va[7]=f2h(as[1]);
    vb = va; vb[6]=f2h(as[2]); vb[7]=f2h(as[3]);
    ushort4v vc = {f2h(ad[0]), f2h(ad[1]), f2h(ad[2]), f2h(ad[3])};
    recA[n] = va;
    recB[n] = vb;
    recC[n] = vc;
  } else {
    int blk = blockIdx.x - nbk1;
    for (int i = t; i < NR; i += 256) lcnt[i] = 0;
    __syncthreads();
    int E4 = E >> 2;
    const i32x4* s4 = (const i32x4*)ei;
    const i32x4* d4 = (const i32x4*)(ei + E);
    for (int i = blk*256 + t; i < E4; i += NB*256){
      i32x4 s = __builtin_nontemporal_load(s4 + i);
      i32x4 d = __builtin_nontemporal_load(d4 + i);
      #pragma unroll
      for (int j = 0; j < 4; ++j){
        int p = d[j] >> PARTBITS;
        int r = atomicAdd(&lcnt[p], 1);
        if (r < SEGCAP){ i32x2 v = {d[j], s[j]}; queue[((size_t)p*NB + blk)*SEGCAP + r] = v; }
      }
    }
    if (blk == 0 && t < (E & 3)){
      int e = E4*4 + t;
      int dd = ei[E + e], ss = ei[e];
      int p = dd >> PARTBITS;
      int r = atomicAdd(&lcnt[p], 1);
      if (r < SEGCAP){ i32x2 v = {dd, ss}; queue[((size_t)p*NB + blk)*SEGCAP + r] = v; }
    }
    __syncthreads();
    for (int i = t; i < NR; i += 256) qcnt[(size_t)i*NB + blk] = lcnt[i];
  }
}

// K2b3: R0 version with ONE change — phase A is the flat 4-thread/segment
// build (R18's isolated −4µs win: no prefix scan, no per-entry binary
// search). Phases B, C byte-identical to R0.
__global__ __launch_bounds__(1024) void k2b3(const i32x2* __restrict__ queue,
    const int* __restrict__ qcnt,
    const ushort8* __restrict__ recA, const ushort8* __restrict__ recB,
    const ushort4v* __restrict__ recC,
    int* __restrict__ cnt, int* __restrict__ row_start,
    int* __restrict__ bucket, int* __restrict__ gtail,
    ushort4v* __restrict__ afh, int nd_bins, int N){
  __shared__ int lc[BINW];
  __shared__ int npref[BINW+1];
  __shared__ int scan[BINW];
  __shared__ int lbuck[BINW*CAP];   // 48KB
  __shared__ int gbase_s;
  int t = threadIdx.x, bin = blockIdx.x;
  // ---- phase A (R24): flat build, 4 threads/segment, direct iteration ----
  if (t < BINW) lc[t] = 0;
  __syncthreads();
  {
    int seg = t >> 2;               // 0..255; guard to NB=240
    if (seg < NB){
      int lq = min(qcnt[(size_t)bin*NB + seg], SEGCAP);
      const i32x2* qs = queue + ((size_t)bin*NB + seg)*SEGCAP;
      for (int j = t & 3; j < lq; j += 4){
        i32x2 pr = qs[j];
        int ld = pr.x & (BINW-1);
        int pos = atomicAdd(&lc[ld], 1);
        if (pos < CAP) lbuck[ld*CAP + pos] = pr.y;
      }
    }
  }
  __syncthreads();
  // ---- phase B: CSR write-out, drone bins only (block-uniform branch) ----
  if (bin < nd_bins){
    if (t < 256) scan[t] = min(lc[t], CAP);
    __syncthreads();
    for (int off = 1; off < 256; off <<= 1){
      int v = 0;
      if (t < 256 && t >= off) v = scan[t - off];
      __syncthreads();
      if (t < 256) scan[t] += v;
      __syncthreads();
    }
    if (t < 256) npref[t] = (t == 0) ? 0 : scan[t-1];
    if (t == 0){
      npref[BINW] = scan[BINW-1];
      gbase_s = atomicAdd(gtail, scan[BINW-1]);
    }
    __syncthreads();
    int gbase = gbase_s;
    int Vn = npref[BINW];
    for (int vi = t; vi < Vn; vi += 1024){
      int lo = 0, hi = BINW-1;
      while (lo < hi){ int mid = (lo+hi+1) >> 1; if (npref[mid] <= vi) lo = mid; else hi = mid-1; }
      bucket[gbase + vi] = lbuck[lo*CAP + (vi - npref[lo])];
    }
    if (t < BINW){
      cnt[bin*BINW + t] = min(lc[t], CAP);
      row_start[bin*BINW + t] = gbase + npref[t];
    }
    __syncthreads();
  }
  // ---- phase C: R15 k3 aggregation, 2 threads/node, bucket from LDS ----
  if (t < 512){
    int dl = t >> 1, hp = t & 1;
    int n = bin*BINW + dl;
    if (n < N){
      const ushort8* R = hp ? recB : recA;
      ushort8 v0 = R[n];
      float xf[6] = {bf2f(v0[0]), bf2f(v0[1]), bf2f(v0[2]), bf2f(v0[3]), bf2f(v0[4]), bf2f(v0[5])};
      float a_s[2] = {h2f(v0[6]), h2f(v0[7])};
      ushort4v cc = recC[n];
      float a_d[2] = {h2f(cc[hp*2]), h2f(cc[hp*2+1])};
      float acc[2][6], den[2];
      #pragma unroll
      for (int h = 0; h < 2; ++h){
        float e0 = __expf(leaky(a_s[h] + a_d[h]));   // self-loop
        den[h] = e0;
        #pragma unroll
        for (int f = 0; f < 6; ++f) acc[h][f] = e0 * xf[f];
      }
      int deg = min(lc[dl], CAP);
      const int* bk = &lbuck[dl*CAP];
      int i = 0;
      for (; i + 4 <= deg; i += 4){
        int sid[4];
        #pragma unroll
        for (int j = 0; j < 4; ++j) sid[j] = bk[i+j];
        ushort8 r[4];
        #pragma unroll
        for (int j = 0; j < 4; ++j) r[j] = R[sid[j]];
        #pragma unroll
        for (int j = 0; j < 4; ++j){
          float sx[6] = {bf2f(r[j][0]), bf2f(r[j][1]), bf2f(r[j][2]),
                         bf2f(r[j][3]), bf2f(r[j][4]), bf2f(r[j][5])};
          float sa[2] = {h2f(r[j][6]), h2f(r[j][7])};
          #pragma unroll
          for (int h = 0; h < 2; ++h){
            float e = __expf(leaky(sa[h] + a_d[h]));
            den[h] += e;
            #pragma unroll
            for (int f = 0; f < 6; ++f) acc[h][f] += e * sx[f];
          }
        }
      }
      for (; i < deg; ++i){
        ushort8 r = R[bk[i]];
        float sx[6] = {bf2f(r[0]), bf2f(r[1]), bf2f(r[2]), bf2f(r[3]), bf2f(r[4]), bf2f(r[5])};
        float sa[2] = {h2f(r[6]), h2f(r[7])};
        #pragma unroll
        for (int h = 0; h < 2; ++h){
          float e = __expf(leaky(sa[h] + a_d[h]));
          den[h] += e;
          #pragma unroll
          for (int f = 0; f < 6; ++f) acc[h][f] += e * sx[f];
        }
      }
      float d0 = 1.f / den[0], d1 = 1.f / den[1];
      ushort4v o0 = {f2h(acc[0][0]*d0), f2h(acc[0][1]*d0), f2h(acc[0][2]*d0), f2h(acc[0][3]*d0)};
      ushort4v o1 = {f2h(acc[0][4]*d0), f2h(acc[0][5]*d0), f2h(acc[1][0]*d1), f2h(acc[1][1]*d1)};
      ushort4v o2 = {f2h(acc[1][2]*d1), f2h(acc[1][3]*d1), f2h(acc[1][4]*d1), f2h(acc[1][5]*d1)};
      size_t ob = (size_t)n*6 + hp*3;
      afh[ob + 0] = o0;
      afh[ob + 1] = o1;
      afh[ob + 2] = o2;
    }
  }
}

// K4 (MFMA + LDS staging): EXACT R0/R15 version.
__global__ __launch_bounds__(256) void k4_mfma(
    const ushort4v* __restrict__ afh, const float* __restrict__ W1,
    const float* __restrict__ b1, const unsigned short* __restrict__ Bfrag,
    const float* __restrict__ as2v, const float* __restrict__ ad2v,
    unsigned short* __restrict__ h2h, float* __restrict__ a2s,
    float* __restrict__ a2d, int N){
  __shared__ float w1s[6*256];     // 6KB
  __shared__ float b1s[256];       // 1KB
  __shared__ ushort8 bfs[2048];    // 32KB
  int t = threadIdx.x;
  {
    const float4* w1g = (const float4*)W1;
    float4* w1l = (float4*)w1s;
    for (int i = t; i < 384; i += 256) w1l[i] = w1g[i];
    if (t < 64) ((float4*)b1s)[t] = ((const float4*)b1)[t];
    const ushort8* bfg = (const ushort8*)Bfrag;
    #pragma unroll
    for (int i = 0; i < 8; ++i) bfs[t + 256*i] = bfg[t + 256*i];
  }
  int L = t & 63;
  int w = t >> 6;
  int base = blockIdx.x * 64;
  int m = L & 15;
  int quad = L >> 4;
  int na = base + w*16 + m;
  int nc = min(na, N-1);
  float af[24];
  {
    const ushort8* A8 = (const ushort8*)(afh + (size_t)nc*6);  // 48B, 16B-aligned
    ushort8 u0 = A8[0], u1 = A8[1], u2 = A8[2];
    #pragma unroll
    for (int j = 0; j < 8; ++j) af[j] = h2f(u0[j]);
    #pragma unroll
    for (int j = 0; j < 8; ++j) af[8+j] = h2f(u1[j]);
    #pragma unroll
    for (int j = 0; j < 8; ++j) af[16+j] = h2f(u2[j]);
  }
  f32x4 acc[4];
  #pragma unroll
  for (int ct = 0; ct < 4; ++ct) acc[ct] = (f32x4){0.f, 0.f, 0.f, 0.f};
  __syncthreads();

  #pragma unroll
  for (int ks = 0; ks < 8; ++ks){
    int kb = ks*32 + quad*8;
    int kc = kb >> 6;
    const float* afk = af + kc*6;
    float4 bb0 = *(const float4*)(b1s + kb);
    float4 bb1 = *(const float4*)(b1s + kb + 4);
    float s0=bb0.x, s1=bb0.y, s2=bb0.z, s3=bb0.w;
    float s4=bb1.x, s5=bb1.y, s6=bb1.z, s7=bb1.w;
    #pragma unroll
    for (int f = 0; f < 6; ++f){
      float a = afk[f];
      float4 w0 = *(const float4*)(w1s + f*256 + kb);
      float4 w1 = *(const float4*)(w1s + f*256 + kb + 4);
      s0 += a*w0.x; s1 += a*w0.y; s2 += a*w0.z; s3 += a*w0.w;
      s4 += a*w1.x; s5 += a*w1.y; s6 += a*w1.z; s7 += a*w1.w;
    }
    ushort8 ap;
    ap[0]=f2bf(eluf(s0)); ap[1]=f2bf(eluf(s1)); ap[2]=f2bf(eluf(s2)); ap[3]=f2bf(eluf(s3));
    ap[4]=f2bf(eluf(s4)); ap[5]=f2bf(eluf(s5)); ap[6]=f2bf(eluf(s6)); ap[7]=f2bf(eluf(s7));
    bf16x8 av = __builtin_bit_cast(bf16x8, ap);
    #pragma unroll
    for (int ct = 0; ct < 4; ++ct){
      bf16x8 bv = __builtin_bit_cast(bf16x8, bfs[(ks*4 + ct)*64 + L]);
      acc[ct] = __builtin_amdgcn_mfma_f32_16x16x32_bf16(av, bv, acc[ct], 0, 0, 0);
    }
  }

  float asv[4], adv[4];
  #pragma unroll
  for (int ct = 0; ct < 4; ++ct){ asv[ct] = as2v[ct*16 + m]; adv[ct] = ad2v[ct*16 + m]; }
  float ps[4] = {0,0,0,0}, pd[4] = {0,0,0,0};
  #pragma unroll
  for (int ct = 0; ct < 4; ++ct)
    #pragma unroll
    for (int r = 0; r < 4; ++r){
      ps[r] += acc[ct][r] * asv[ct];
      pd[r] += acc[ct][r] * adv[ct];
    }
  #pragma unroll
  for (int r = 0; r < 4; ++r){
    int nr = base + w*16 + quad*4 + r;
    if (nr < N){
      #pragma unroll
      for (int ct = 0; ct < 4; ++ct)
        h2h[(size_t)nr*64 + ct*16 + m] = f2h(acc[ct][r]);
    }
  }
  #pragma unroll
  for (int mask = 1; mask <= 8; mask <<= 1){
    #pragma unroll
    for (int r = 0; r < 4; ++r){
      ps[r] += __shfl_xor(ps[r], mask, 64);
      pd[r] += __shfl_xor(pd[r], mask, 64);
    }
  }
  if (m == 0){
    #pragma unroll
    for (int r = 0; r < 4; ++r){
      int nr = base + w*16 + quad*4 + r;
      if (nr < N){ a2s[nr] = ps[r]; a2d[nr] = pd[r]; }
    }
  }
}

// K5: layer-2 aggregation only for drone dsts (first ND) + elu + MLP head.
// EXACT R0/R15 version.
__global__ __launch_bounds__(256) void k5_out(
    const unsigned short* __restrict__ h2h, const float* __restrict__ a2s,
    const float* __restrict__ a2d, const int* __restrict__ cnt,
    const int* __restrict__ row_start, const int* __restrict__ bucket,
    const float* __restrict__ b2, const float* __restrict__ fc1w,
    const float* __restrict__ fc1b, const float* __restrict__ fc2w,
    const float* __restrict__ fc2b, float* __restrict__ out, int ND){
  __shared__ float hb[4][64];
  int lane = threadIdx.x & 63;
  int w = threadIdx.x >> 6;
  int n = blockIdx.x * 4 + w;
  if (n >= ND) return;
  float adv = a2d[n];
  float e0 = __expf(leaky(a2s[n] + adv));
  float den = e0;
  float acc = e0 * h2f(h2h[(size_t)n*64 + lane]);
  int deg = cnt[n];
  const int* bk = bucket + row_start[n];
  int i = 0;
  for (; i + 4 <= deg; i += 4){
    int sid[4];
    #pragma unroll
    for (int j = 0; j < 4; ++j) sid[j] = bk[i+j];
    float av[4]; unsigned short hv4[4];
    #pragma unroll
    for (int j = 0; j < 4; ++j){
      av[j] = a2s[sid[j]];
      hv4[j] = h2h[(size_t)sid[j]*64 + lane];
    }
    #pragma unroll
    for (int j = 0; j < 4; ++j){
      float e = __expf(leaky(av[j] + adv));
      den += e;
      acc += e * h2f(hv4[j]);
    }
  }
  for (; i < deg; ++i){
    int s = bk[i];
    float e = __expf(leaky(a2s[s] + adv));
    den += e;
    acc += e * h2f(h2h[(size_t)s*64 + lane]);
  }
  float hv = eluf(acc / den + b2[lane]);
  hb[w][lane] = hv;               // wave-local LDS (lockstep wave64)
  float t1 = fc1b[lane];
  for (int k = 0; k < 64; ++k) t1 += hb[w][k] * fc1w[k*64 + lane];
  t1 = fmaxf(t1, 0.f);
  float p0 = t1 * fc2w[lane*2 + 0];
  float p1 = t1 * fc2w[lane*2 + 1];
  for (int o = 32; o > 0; o >>= 1){
    p0 += __shfl_down(p0, o, 64);
    p1 += __shfl_down(p1, o, 64);
  }
  if (lane == 0){
    out[n*2 + 0] = tanhf(p0 + fc2b[0]) * 2.f;
    out[n*2 + 1] = tanhf(p1 + fc2b[1]) * 2.f;
  }
}

extern "C" void kernel_launch(void* const* d_in, const int* in_sizes, int n_in,
                              void* d_out, int out_size, void* d_ws, size_t ws_size,
                              hipStream_t stream){
  const float* x    = (const float*)d_in[0];
  const int*   ei   = (const int*)d_in[1];    // harness passes integers as int32
  const float* W1   = (const float*)d_in[3];
  const float* as1  = (const float*)d_in[4];
  const float* ad1  = (const float*)d_in[5];
  const float* b1   = (const float*)d_in[6];
  const float* W2   = (const float*)d_in[7];
  const float* as2  = (const float*)d_in[8];
  const float* ad2  = (const float*)d_in[9];
  const float* b2   = (const float*)d_in[10];
  const float* fc1w = (const float*)d_in[11];
  const float* fc1b = (const float*)d_in[12];
  const float* fc2w = (const float*)d_in[13];
  const float* fc2b = (const float*)d_in[14];
  float* out = (float*)d_out;

  int N  = in_sizes[0] / 6;
  int E  = in_sizes[1] / 2;
  int ND = out_size / 2;
  int NR = (N + BINW - 1) >> PARTBITS;   // number of dst bins
  int nd_bins = (ND + BINW - 1) / BINW;  // bins containing drone dsts (k5)
  int nbk1 = (N + 255) / 256;

  char* p = (char*)d_ws;
  auto alloc = [&](size_t bytes){ void* r = (void*)p; p += (bytes + 255) & ~(size_t)255; return r; };
  int*            cnt    = (int*)           alloc((size_t)NR * BINW * 4);
  int*            rowst  = (int*)           alloc((size_t)NR * BINW * 4);
  int*            bucket = (int*)           alloc(((size_t)E + 1024) * 4);   // CSR (drone bins only)
  ushort8*        recA   = (ushort8*)       alloc((size_t)N * 16);
  ushort8*        recB   = (ushort8*)       alloc((size_t)N * 16);
  ushort4v*       recC   = (ushort4v*)      alloc((size_t)N * 8);
  ushort4v*       afh    = (ushort4v*)      alloc((size_t)N * 48);
  unsigned short* h2h    = (unsigned short*)alloc((size_t)N * 128);
  float*          a2s    = (float*)         alloc((size_t)N * 4);
  float*          a2d    = (float*)         alloc((size_t)N * 4);
  unsigned short* Bfrag  = (unsigned short*)alloc(16384 * 2);
  i32x2*          queue  = (i32x2*)         alloc((size_t)NR * NB * SEGCAP * 8);
  int*            qcnt   = (int*)           alloc((size_t)NR * NB * 4);
  int*            gtail  = (int*)           alloc(256);

  size_t needed = (size_t)(p - (char*)d_ws);
  if (needed > ws_size) return;   // clean fail instead of GPU fault

  k12a<<<nbk1 + NB, 256, 0, stream>>>(x, W1, as1, ad1, W2, Bfrag, recA, recB,
                                      recC, gtail, N, nbk1, ei, E, NR, queue, qcnt);
  k2b3<<<NR, 1024, 0, stream>>>(queue, qcnt, recA, recB, recC,
                                cnt, rowst, bucket, gtail, afh, nd_bins, N);
  k4_mfma<<<(N + 63)/64, 256, 0, stream>>>(afh, W1, b1, Bfrag, as2, ad2,
                                           h2h, a2s, a2d, N);
  k5_out<<<(ND + 3)/4, 256, 0, stream>>>(h2h, a2s, a2d, cnt, rowst, bucket, b2,
                                         fc1w, fc1b, fc2w, fc2b, out, ND);
}

// Round 9
// 167.802 us; speedup vs baseline: 2.7164x; 1.0327x over previous
//
#include <hip/hip_runtime.h>
#include <hip/hip_fp16.h>
#include <math.h>

#define CAP 48       // max bucketed in-degree; Poisson(16), P(deg>=48) ~ 8e-11/node
#define PARTBITS 8   // 256 dsts per bin
#define BINW 256
#define NB 240       // routing blocks
#define SEGCAP 48    // per-(bin,block) queue segment; mean 17, 7.5 sigma

typedef float f32x4 __attribute__((ext_vector_type(4)));
typedef __bf16 bf16x8 __attribute__((ext_vector_type(8)));
typedef unsigned short ushort8 __attribute__((ext_vector_type(8)));
typedef unsigned short ushort4v __attribute__((ext_vector_type(4)));
typedef int i32x4 __attribute__((ext_vector_type(4)));

__device__ __forceinline__ float leaky(float x){ return x > 0.f ? x : 0.2f * x; }
__device__ __forceinline__ float eluf(float x){ return x > 0.f ? x : __expf(x) - 1.f; }
__device__ __forceinline__ unsigned short f2bf(float f){  // RNE float->bf16
  unsigned u = __float_as_uint(f);
  u += 0x7FFF + ((u >> 16) & 1);
  return (unsigned short)(u >> 16);
}
__device__ __forceinline__ float bf2f(unsigned short u){
  return __uint_as_float(((unsigned)u) << 16);
}
__device__ __forceinline__ unsigned short f2h(float f){
  return __half_as_ushort(__float2half(f));
}
__device__ __forceinline__ float h2f(unsigned short u){
  return __half2float(__ushort_as_half(u));
}

// K12a: fused k1 (node records + Bfrag prepack) and k2a (edge routing).
// R25: queue entries packed to 4B: (src << 8) | (dst & 255); bin implied
// by queue position (halves scattered queue write + k2b3 read footprint).
// Otherwise EXACT R0/R15 version.
__global__ __launch_bounds__(256) void k12a(const float* __restrict__ x,
    const float* __restrict__ W1, const float* __restrict__ as1,
    const float* __restrict__ ad1, const float* __restrict__ W2,
    unsigned short* __restrict__ Bfrag, ushort8* __restrict__ recA,
    ushort8* __restrict__ recB, ushort4v* __restrict__ recC,
    int* __restrict__ gtail, int N, int nbk1,
    const int* __restrict__ ei, int E, int NR,
    unsigned* __restrict__ queue, int* __restrict__ qcnt){
  __shared__ float vw[48];
  __shared__ int lcnt[512];
  int t = threadIdx.x;
  if ((int)blockIdx.x < nbk1){
    int gid = blockIdx.x * 256 + t;
    if (gid == 0) *gtail = 0;   // CSR allocator, consumed by k2b3
    if (gid < 16384){
      int j  = gid & 7;
      int L  = (gid >> 3) & 63;
      int ct = (gid >> 9) & 3;
      int ks = gid >> 11;
      int k = ks*32 + ((L >> 4) & 3)*8 + j;
      int c = ct*16 + (L & 15);
      Bfrag[gid] = f2bf(W2[k*64 + c]);
    }
    if (t < 48){
      int side = t / 24, r = t % 24, f = r / 4, h = r % 4;
      const float* att = side ? ad1 : as1;
      float s = 0.f;
      for (int c = 0; c < 64; ++c) s += W1[f*256 + h*64 + c] * att[h*64 + c];
      vw[side*24 + f*4 + h] = s;
    }
    __syncthreads();
    int n = gid;
    if (n >= N) return;
    float xf[6];
    for (int f = 0; f < 6; ++f) xf[f] = x[n*6 + f];
    float as[4], ad[4];
    for (int h = 0; h < 4; ++h){
      float s = 0.f, d = 0.f;
      for (int f = 0; f < 6; ++f){ s += xf[f] * vw[f*4 + h]; d += xf[f] * vw[24 + f*4 + h]; }
      as[h] = s; ad[h] = d;
    }
    ushort8 va, vb;
    va[0]=f2bf(xf[0]); va[1]=f2bf(xf[1]); va[2]=f2bf(xf[2]); va[3]=f2bf(xf[3]);
    va[4]=f2bf(xf[4]); va[5]=f2bf(xf[5]); va[6]=f2h(as[0]); va[7]=f2h(as[1]);
    vb = va; vb[6]=f2h(as[2]); vb[7]=f2h(as[3]);
    ushort4v vc = {f2h(ad[0]), f2h(ad[1]), f2h(ad[2]), f2h(ad[3])};
    recA[n] = va;
    recB[n] = vb;
    recC[n] = vc;
  } else {
    int blk = blockIdx.x - nbk1;
    for (int i = t; i < NR; i += 256) lcnt[i] = 0;
    __syncthreads();
    int E4 = E >> 2;
    const i32x4* s4 = (const i32x4*)ei;
    const i32x4* d4 = (const i32x4*)(ei + E);
    for (int i = blk*256 + t; i < E4; i += NB*256){
      i32x4 s = __builtin_nontemporal_load(s4 + i);
      i32x4 d = __builtin_nontemporal_load(d4 + i);
      #pragma unroll
      for (int j = 0; j < 4; ++j){
        int p = d[j] >> PARTBITS;
        int r = atomicAdd(&lcnt[p], 1);
        if (r < SEGCAP){
          unsigned v = ((unsigned)s[j] << PARTBITS) | ((unsigned)d[j] & (BINW-1u));
          queue[((size_t)p*NB + blk)*SEGCAP + r] = v;
        }
      }
    }
    if (blk == 0 && t < (E & 3)){
      int e = E4*4 + t;
      int dd = ei[E + e], ss = ei[e];
      int p = dd >> PARTBITS;
      int r = atomicAdd(&lcnt[p], 1);
      if (r < SEGCAP){
        unsigned v = ((unsigned)ss << PARTBITS) | ((unsigned)dd & (BINW-1u));
        queue[((size_t)p*NB + blk)*SEGCAP + r] = v;
      }
    }
    __syncthreads();
    for (int i = t; i < NR; i += 256) qcnt[(size_t)i*NB + blk] = lcnt[i];
  }
}

// K2b3: R24 version (R0 + flat phase A), queue reads now 4B packed.
// Phases B, C byte-identical to R0.
__global__ __launch_bounds__(1024) void k2b3(const unsigned* __restrict__ queue,
    const int* __restrict__ qcnt,
    const ushort8* __restrict__ recA, const ushort8* __restrict__ recB,
    const ushort4v* __restrict__ recC,
    int* __restrict__ cnt, int* __restrict__ row_start,
    int* __restrict__ bucket, int* __restrict__ gtail,
    ushort4v* __restrict__ afh, int nd_bins, int N){
  __shared__ int lc[BINW];
  __shared__ int npref[BINW+1];
  __shared__ int scan[BINW];
  __shared__ int lbuck[BINW*CAP];   // 48KB
  __shared__ int gbase_s;
  int t = threadIdx.x, bin = blockIdx.x;
  // ---- phase A: flat build, 4 threads/segment, direct iteration ----
  if (t < BINW) lc[t] = 0;
  __syncthreads();
  {
    int seg = t >> 2;               // 0..255; guard to NB=240
    if (seg < NB){
      int lq = min(qcnt[(size_t)bin*NB + seg], SEGCAP);
      const unsigned* qs = queue + ((size_t)bin*NB + seg)*SEGCAP;
      for (int j = t & 3; j < lq; j += 4){
        unsigned pr = qs[j];
        int ld = (int)(pr & (BINW-1u));
        int pos = atomicAdd(&lc[ld], 1);
        if (pos < CAP) lbuck[ld*CAP + pos] = (int)(pr >> PARTBITS);
      }
    }
  }
  __syncthreads();
  // ---- phase B: CSR write-out, drone bins only (block-uniform branch) ----
  if (bin < nd_bins){
    if (t < 256) scan[t] = min(lc[t], CAP);
    __syncthreads();
    for (int off = 1; off < 256; off <<= 1){
      int v = 0;
      if (t < 256 && t >= off) v = scan[t - off];
      __syncthreads();
      if (t < 256) scan[t] += v;
      __syncthreads();
    }
    if (t < 256) npref[t] = (t == 0) ? 0 : scan[t-1];
    if (t == 0){
      npref[BINW] = scan[BINW-1];
      gbase_s = atomicAdd(gtail, scan[BINW-1]);
    }
    __syncthreads();
    int gbase = gbase_s;
    int Vn = npref[BINW];
    for (int vi = t; vi < Vn; vi += 1024){
      int lo = 0, hi = BINW-1;
      while (lo < hi){ int mid = (lo+hi+1) >> 1; if (npref[mid] <= vi) lo = mid; else hi = mid-1; }
      bucket[gbase + vi] = lbuck[lo*CAP + (vi - npref[lo])];
    }
    if (t < BINW){
      cnt[bin*BINW + t] = min(lc[t], CAP);
      row_start[bin*BINW + t] = gbase + npref[t];
    }
    __syncthreads();
  }
  // ---- phase C: R15 k3 aggregation, 2 threads/node, bucket from LDS ----
  if (t < 512){
    int dl = t >> 1, hp = t & 1;
    int n = bin*BINW + dl;
    if (n < N){
      const ushort8* R = hp ? recB : recA;
      ushort8 v0 = R[n];
      float xf[6] = {bf2f(v0[0]), bf2f(v0[1]), bf2f(v0[2]), bf2f(v0[3]), bf2f(v0[4]), bf2f(v0[5])};
      float a_s[2] = {h2f(v0[6]), h2f(v0[7])};
      ushort4v cc = recC[n];
      float a_d[2] = {h2f(cc[hp*2]), h2f(cc[hp*2+1])};
      float acc[2][6], den[2];
      #pragma unroll
      for (int h = 0; h < 2; ++h){
        float e0 = __expf(leaky(a_s[h] + a_d[h]));   // self-loop
        den[h] = e0;
        #pragma unroll
        for (int f = 0; f < 6; ++f) acc[h][f] = e0 * xf[f];
      }
      int deg = min(lc[dl], CAP);
      const int* bk = &lbuck[dl*CAP];
      int i = 0;
      for (; i + 4 <= deg; i += 4){
        int sid[4];
        #pragma unroll
        for (int j = 0; j < 4; ++j) sid[j] = bk[i+j];
        ushort8 r[4];
        #pragma unroll
        for (int j = 0; j < 4; ++j) r[j] = R[sid[j]];
        #pragma unroll
        for (int j = 0; j < 4; ++j){
          float sx[6] = {bf2f(r[j][0]), bf2f(r[j][1]), bf2f(r[j][2]),
                         bf2f(r[j][3]), bf2f(r[j][4]), bf2f(r[j][5])};
          float sa[2] = {h2f(r[j][6]), h2f(r[j][7])};
          #pragma unroll
          for (int h = 0; h < 2; ++h){
            float e = __expf(leaky(sa[h] + a_d[h]));
            den[h] += e;
            #pragma unroll
            for (int f = 0; f < 6; ++f) acc[h][f] += e * sx[f];
          }
        }
      }
      for (; i < deg; ++i){
        ushort8 r = R[bk[i]];
        float sx[6] = {bf2f(r[0]), bf2f(r[1]), bf2f(r[2]), bf2f(r[3]), bf2f(r[4]), bf2f(r[5])};
        float sa[2] = {h2f(r[6]), h2f(r[7])};
        #pragma unroll
        for (int h = 0; h < 2; ++h){
          float e = __expf(leaky(sa[h] + a_d[h]));
          den[h] += e;
          #pragma unroll
          for (int f = 0; f < 6; ++f) acc[h][f] += e * sx[f];
        }
      }
      float d0 = 1.f / den[0], d1 = 1.f / den[1];
      ushort4v o0 = {f2h(acc[0][0]*d0), f2h(acc[0][1]*d0), f2h(acc[0][2]*d0), f2h(acc[0][3]*d0)};
      ushort4v o1 = {f2h(acc[0][4]*d0), f2h(acc[0][5]*d0), f2h(acc[1][0]*d1), f2h(acc[1][1]*d1)};
      ushort4v o2 = {f2h(acc[1][2]*d1), f2h(acc[1][3]*d1), f2h(acc[1][4]*d1), f2h(acc[1][5]*d1)};
      size_t ob = (size_t)n*6 + hp*3;
      afh[ob + 0] = o0;
      afh[ob + 1] = o1;
      afh[ob + 2] = o2;
    }
  }
}

// K4 (MFMA + LDS staging): EXACT R0/R15 version.
__global__ __launch_bounds__(256) void k4_mfma(
    const ushort4v* __restrict__ afh, const float* __restrict__ W1,
    const float* __restrict__ b1, const unsigned short* __restrict__ Bfrag,
    const float* __restrict__ as2v, const float* __restrict__ ad2v,
    unsigned short* __restrict__ h2h, float* __restrict__ a2s,
    float* __restrict__ a2d, int N){
  __shared__ float w1s[6*256];     // 6KB
  __shared__ float b1s[256];       // 1KB
  __shared__ ushort8 bfs[2048];    // 32KB
  int t = threadIdx.x;
  {
    const float4* w1g = (const float4*)W1;
    float4* w1l = (float4*)w1s;
    for (int i = t; i < 384; i += 256) w1l[i] = w1g[i];
    if (t < 64) ((float4*)b1s)[t] = ((const float4*)b1)[t];
    const ushort8* bfg = (const ushort8*)Bfrag;
    #pragma unroll
    for (int i = 0; i < 8; ++i) bfs[t + 256*i] = bfg[t + 256*i];
  }
  int L = t & 63;
  int w = t >> 6;
  int base = blockIdx.x * 64;
  int m = L & 15;
  int quad = L >> 4;
  int na = base + w*16 + m;
  int nc = min(na, N-1);
  float af[24];
  {
    const ushort8* A8 = (const ushort8*)(afh + (size_t)nc*6);  // 48B, 16B-aligned
    ushort8 u0 = A8[0], u1 = A8[1], u2 = A8[2];
    #pragma unroll
    for (int j = 0; j < 8; ++j) af[j] = h2f(u0[j]);
    #pragma unroll
    for (int j = 0; j < 8; ++j) af[8+j] = h2f(u1[j]);
    #pragma unroll
    for (int j = 0; j < 8; ++j) af[16+j] = h2f(u2[j]);
  }
  f32x4 acc[4];
  #pragma unroll
  for (int ct = 0; ct < 4; ++ct) acc[ct] = (f32x4){0.f, 0.f, 0.f, 0.f};
  __syncthreads();

  #pragma unroll
  for (int ks = 0; ks < 8; ++ks){
    int kb = ks*32 + quad*8;
    int kc = kb >> 6;
    const float* afk = af + kc*6;
    float4 bb0 = *(const float4*)(b1s + kb);
    float4 bb1 = *(const float4*)(b1s + kb + 4);
    float s0=bb0.x, s1=bb0.y, s2=bb0.z, s3=bb0.w;
    float s4=bb1.x, s5=bb1.y, s6=bb1.z, s7=bb1.w;
    #pragma unroll
    for (int f = 0; f < 6; ++f){
      float a = afk[f];
      float4 w0 = *(const float4*)(w1s + f*256 + kb);
      float4 w1 = *(const float4*)(w1s + f*256 + kb + 4);
      s0 += a*w0.x; s1 += a*w0.y; s2 += a*w0.z; s3 += a*w0.w;
      s4 += a*w1.x; s5 += a*w1.y; s6 += a*w1.z; s7 += a*w1.w;
    }
    ushort8 ap;
    ap[0]=f2bf(eluf(s0)); ap[1]=f2bf(eluf(s1)); ap[2]=f2bf(eluf(s2)); ap[3]=f2bf(eluf(s3));
    ap[4]=f2bf(eluf(s4)); ap[5]=f2bf(eluf(s5)); ap[6]=f2bf(eluf(s6)); ap[7]=f2bf(eluf(s7));
    bf16x8 av = __builtin_bit_cast(bf16x8, ap);
    #pragma unroll
    for (int ct = 0; ct < 4; ++ct){
      bf16x8 bv = __builtin_bit_cast(bf16x8, bfs[(ks*4 + ct)*64 + L]);
      acc[ct] = __builtin_amdgcn_mfma_f32_16x16x32_bf16(av, bv, acc[ct], 0, 0, 0);
    }
  }

  float asv[4], adv[4];
  #pragma unroll
  for (int ct = 0; ct < 4; ++ct){ asv[ct] = as2v[ct*16 + m]; adv[ct] = ad2v[ct*16 + m]; }
  float ps[4] = {0,0,0,0}, pd[4] = {0,0,0,0};
  #pragma unroll
  for (int ct = 0; ct < 4; ++ct)
    #pragma unroll
    for (int r = 0; r < 4; ++r){
      ps[r] += acc[ct][r] * asv[ct];
      pd[r] += acc[ct][r] * adv[ct];
    }
  #pragma unroll
  for (int r = 0; r < 4; ++r){
    int nr = base + w*16 + quad*4 + r;
    if (nr < N){
      #pragma unroll
      for (int ct = 0; ct < 4; ++ct)
        h2h[(size_t)nr*64 + ct*16 + m] = f2h(acc[ct][r]);
    }
  }
  #pragma unroll
  for (int mask = 1; mask <= 8; mask <<= 1){
    #pragma unroll
    for (int r = 0; r < 4; ++r){
      ps[r] += __shfl_xor(ps[r], mask, 64);
      pd[r] += __shfl_xor(pd[r], mask, 64);
    }
  }
  if (m == 0){
    #pragma unroll
    for (int r = 0; r < 4; ++r){
      int nr = base + w*16 + quad*4 + r;
      if (nr < N){ a2s[nr] = ps[r]; a2d[nr] = pd[r]; }
    }
  }
}

// K5: layer-2 aggregation only for drone dsts (first ND) + elu + MLP head.
// EXACT R0/R15 version.
__global__ __launch_bounds__(256) void k5_out(
    const unsigned short* __restrict__ h2h, const float* __restrict__ a2s,
    const float* __restrict__ a2d, const int* __restrict__ cnt,
    const int* __restrict__ row_start, const int* __restrict__ bucket,
    const float* __restrict__ b2, const float* __restrict__ fc1w,
    const float* __restrict__ fc1b, const float* __restrict__ fc2w,
    const float* __restrict__ fc2b, float* __restrict__ out, int ND){
  __shared__ float hb[4][64];
  int lane = threadIdx.x & 63;
  int w = threadIdx.x >> 6;
  int n = blockIdx.x * 4 + w;
  if (n >= ND) return;
  float adv = a2d[n];
  float e0 = __expf(leaky(a2s[n] + adv));
  float den = e0;
  float acc = e0 * h2f(h2h[(size_t)n*64 + lane]);
  int deg = cnt[n];
  const int* bk = bucket + row_start[n];
  int i = 0;
  for (; i + 4 <= deg; i += 4){
    int sid[4];
    #pragma unroll
    for (int j = 0; j < 4; ++j) sid[j] = bk[i+j];
    float av[4]; unsigned short hv4[4];
    #pragma unroll
    for (int j = 0; j < 4; ++j){
      av[j] = a2s[sid[j]];
      hv4[j] = h2h[(size_t)sid[j]*64 + lane];
    }
    #pragma unroll
    for (int j = 0; j < 4; ++j){
      float e = __expf(leaky(av[j] + adv));
      den += e;
      acc += e * h2f(hv4[j]);
    }
  }
  for (; i < deg; ++i){
    int s = bk[i];
    float e = __expf(leaky(a2s[s] + adv));
    den += e;
    acc += e * h2f(h2h[(size_t)s*64 + lane]);
  }
  float hv = eluf(acc / den + b2[lane]);
  hb[w][lane] = hv;               // wave-local LDS (lockstep wave64)
  float t1 = fc1b[lane];
  for (int k = 0; k < 64; ++k) t1 += hb[w][k] * fc1w[k*64 + lane];
  t1 = fmaxf(t1, 0.f);
  float p0 = t1 * fc2w[lane*2 + 0];
  float p1 = t1 * fc2w[lane*2 + 1];
  for (int o = 32; o > 0; o >>= 1){
    p0 += __shfl_down(p0, o, 64);
    p1 += __shfl_down(p1, o, 64);
  }
  if (lane == 0){
    out[n*2 + 0] = tanhf(p0 + fc2b[0]) * 2.f;
    out[n*2 + 1] = tanhf(p1 + fc2b[1]) * 2.f;
  }
}

extern "C" void kernel_launch(void* const* d_in, const int* in_sizes, int n_in,
                              void* d_out, int out_size, void* d_ws, size_t ws_size,
                              hipStream_t stream){
  const float* x    = (const float*)d_in[0];
  const int*   ei   = (const int*)d_in[1];    // harness passes integers as int32
  const float* W1   = (const float*)d_in[3];
  const float* as1  = (const float*)d_in[4];
  const float* ad1  = (const float*)d_in[5];
  const float* b1   = (const float*)d_in[6];
  const float* W2   = (const float*)d_in[7];
  const float* as2  = (const float*)d_in[8];
  const float* ad2  = (const float*)d_in[9];
  const float* b2   = (const float*)d_in[10];
  const float* fc1w = (const float*)d_in[11];
  const float* fc1b = (const float*)d_in[12];
  const float* fc2w = (const float*)d_in[13];
  const float* fc2b = (const float*)d_in[14];
  float* out = (float*)d_out;

  int N  = in_sizes[0] / 6;
  int E  = in_sizes[1] / 2;
  int ND = out_size / 2;
  int NR = (N + BINW - 1) >> PARTBITS;   // number of dst bins
  int nd_bins = (ND + BINW - 1) / BINW;  // bins containing drone dsts (k5)
  int nbk1 = (N + 255) / 256;

  char* p = (char*)d_ws;
  auto alloc = [&](size_t bytes){ void* r = (void*)p; p += (bytes + 255) & ~(size_t)255; return r; };
  int*            cnt    = (int*)           alloc((size_t)NR * BINW * 4);
  int*            rowst  = (int*)           alloc((size_t)NR * BINW * 4);
  int*            bucket = (int*)           alloc(((size_t)E + 1024) * 4);   // CSR (drone bins only)
  ushort8*        recA   = (ushort8*)       alloc((size_t)N * 16);
  ushort8*        recB   = (ushort8*)       alloc((size_t)N * 16);
  ushort4v*       recC   = (ushort4v*)      alloc((size_t)N * 8);
  ushort4v*       afh    = (ushort4v*)      alloc((size_t)N * 48);
  unsigned short* h2h    = (unsigned short*)alloc((size_t)N * 128);
  float*          a2s    = (float*)         alloc((size_t)N * 4);
  float*          a2d    = (float*)         alloc((size_t)N * 4);
  unsigned short* Bfrag  = (unsigned short*)alloc(16384 * 2);
  unsigned*       queue  = (unsigned*)      alloc((size_t)NR * NB * SEGCAP * 4);
  int*            qcnt   = (int*)           alloc((size_t)NR * NB * 4);
  int*            gtail  = (int*)           alloc(256);

  size_t needed = (size_t)(p - (char*)d_ws);
  if (needed > ws_size) return;   // clean fail instead of GPU fault

  k12a<<<nbk1 + NB, 256, 0, stream>>>(x, W1, as1, ad1, W2, Bfrag, recA, recB,
                                      recC, gtail, N, nbk1, ei, E, NR, queue, qcnt);
  k2b3<<<NR, 1024, 0, stream>>>(queue, qcnt, recA, recB, recC,
                                cnt, rowst, bucket, gtail, afh, nd_bins, N);
  k4_mfma<<<(N + 63)/64, 256, 0, stream>>>(afh, W1, b1, Bfrag, as2, ad2,
                                           h2h, a2s, a2d, N);
  k5_out<<<(ND + 3)/4, 256, 0, stream>>>(h2h, a2s, a2d, cnt, rowst, bucket, b2,
                                         fc1w, fc1b, fc2w, fc2b, out, ND);
}